// Round 13
// baseline (239.969 us; speedup 1.0000x reference)
//
#include <hip/hip_runtime.h>
#include <hip/hip_bf16.h>
#include <math.h>

typedef unsigned short ushort;
typedef __attribute__((ext_vector_type(4))) float f32x4;
typedef __attribute__((ext_vector_type(8))) short s16x8;
typedef __attribute__((ext_vector_type(4))) short s16x4;
typedef __attribute__((ext_vector_type(4))) ushort u16x4;

#define H_    64
#define W_    64
#define DIM   160
#define HEADS 5
#define KD    32
#define WS    14
#define NTOK  196
#define NWIN  400
#define HIDDEN 640
#define EPS   1e-5f
#define NROW  (NWIN*NTOK)    // 78400
#define BATCH 16
#define L_    (H_*W_)
#define MROW  (BATCH*L_)     // 65536
#define CS    0.25507875861f   // (1/sqrt(32)) * log2(e)
#define GSTRIPS 4

#if __has_builtin(__builtin_amdgcn_exp2f)
#define EXP2(x) __builtin_amdgcn_exp2f(x)
#else
#define EXP2(x) exp2f(x)
#endif

__device__ __forceinline__ ushort f2bfbits(float f) {
    unsigned u = __float_as_uint(f);
    unsigned r = (u + 0x7fffu + ((u >> 16) & 1u)) >> 16;
    return (ushort)r;
}
__device__ __forceinline__ float bf2f(ushort u) {
    return __uint_as_float(((unsigned)u) << 16);
}

// ---------------------------------------------------------------- pre kernel
// wb: [0,76800) qkv_w | [76800,102400) proj_w | [102400,204800) W1pack
// | [204800,307200) W2pack (all bf16).  biasPb: bf16 C-layout bias tiles,
// pre-scaled by log2e: biasPb[((h*13+qt)*13+kt)*1024 + ln*4 + r].
__global__ __launch_bounds__(256) void pre_kernel(
    const float* __restrict__ qkv_w, const float* __restrict__ proj_w,
    const float* __restrict__ fc1_w, const float* __restrict__ fc2_w,
    const float* __restrict__ conv_w, const float* __restrict__ bn_g,
    const float* __restrict__ abias, const int* __restrict__ bidx,
    ushort* __restrict__ wb, float* __restrict__ cwT,
    ushort* __restrict__ biasPb, int n_off)
{
    const int gid = blockIdx.x * 256 + threadIdx.x;
    if (gid < 19200) {
        float4 v = ((const float4*)qkv_w)[gid];
        u16x4 o = { f2bfbits(v.x), f2bfbits(v.y), f2bfbits(v.z), f2bfbits(v.w) };
        *(u16x4*)(wb + gid * 4) = o;
    } else if (gid < 25600) {
        const int i = gid - 19200;
        float4 v = ((const float4*)proj_w)[i];
        u16x4 o = { f2bfbits(v.x), f2bfbits(v.y), f2bfbits(v.z), f2bfbits(v.w) };
        *(u16x4*)(wb + 76800 + i * 4) = o;
    } else if (gid < 38400) {
        const int idx = gid - 25600;          // [0,12800)
        const int l = idx & 63, rest = idx >> 6;
        const int jj = rest % 5, ht = rest / 5;
        const float* src = fc1_w + (size_t)(ht * 16 + (l & 15)) * 160
                         + jj * 32 + (l >> 4) * 8;
        const float4 v0 = *(const float4*)src;
        const float4 v1 = *(const float4*)(src + 4);
        u16x4 o0 = { f2bfbits(v0.x), f2bfbits(v0.y), f2bfbits(v0.z), f2bfbits(v0.w) };
        u16x4 o1 = { f2bfbits(v1.x), f2bfbits(v1.y), f2bfbits(v1.z), f2bfbits(v1.w) };
        *(u16x4*)(wb + 102400 + idx * 8)     = o0;
        *(u16x4*)(wb + 102400 + idx * 8 + 4) = o1;
    } else if (gid < 51200) {
        const int idx = gid - 38400;          // [0,12800)
        const int l = idx & 63, f = idx >> 6; // f in [0,200)
        const int dt = f % 10, u = f / 10;
        const float* base = fc2_w + (size_t)(dt * 16 + (l & 15)) * HIDDEN
                          + u * 32 + 4 * (l >> 4);
        const float4 v0 = *(const float4*)base;          // i=0..3 (even tile)
        const float4 v1 = *(const float4*)(base + 16);   // i=4..7 (odd tile)
        u16x4 o0 = { f2bfbits(v0.x), f2bfbits(v0.y), f2bfbits(v0.z), f2bfbits(v0.w) };
        u16x4 o1 = { f2bfbits(v1.x), f2bfbits(v1.y), f2bfbits(v1.z), f2bfbits(v1.w) };
        *(u16x4*)(wb + 204800 + idx * 8)     = o0;
        *(u16x4*)(wb + 204800 + idx * 8 + 4) = o1;
    } else if (gid < 51560) {
        const int i = gid - 51200;
        const int t = i / 40, c4 = (i % 40) * 4;
#pragma unroll
        for (int j = 0; j < 4; ++j) {
            const int c = c4 + j;
            cwT[t * DIM + c] = conv_w[c * 9 + t] * bn_g[c] * rsqrtf(1.0f + EPS);
        }
    } else if (gid < 267880) {
        const int idx = gid - 51560;          // [0,216320)
        const int ln = idx & 255, f = idx >> 8;  // f in [0,845)
        const int h = f / 169, rem = f % 169;
        const int qt = rem / 13, kt = rem % 13;
        int q = qt * 16 + (ln & 15); if (q > NTOK - 1) q = NTOK - 1;
        const int k0 = kt * 16 + (ln >> 4) * 4;
        ushort o[4];
#pragma unroll
        for (int r = 0; r < 4; ++r) {
            const int k = k0 + r;
            o[r] = (k < NTOK)
                ? f2bfbits(abias[h * n_off + bidx[q * NTOK + k]] * 1.4426950408889634f)
                : (ushort)0;
        }
        *(u16x4*)(biasPb + (size_t)idx * 4) = *(const u16x4*)o;
    }
}

// ---------------------------------------------------------------- LN1
__global__ __launch_bounds__(256) void ln1_win_kernel(
    const float* __restrict__ x, const float* __restrict__ g,
    const float* __restrict__ b, ushort* __restrict__ xn)
{
    const int row = blockIdx.x * 4 + (threadIdx.x >> 6);
    const int win = row / NTOK, tok = row % NTOK;
    const int bb = win / 25, wr = (win % 25) / 5, wc = win % 5;
    const int gh = wr * WS + tok / WS, gw = wc * WS + tok % WS;
    const bool valid = (gh < H_) && (gw < W_);
    const float* xrow = x + ((size_t)bb * L_ + (size_t)gh * W_ + gw) * DIM;
    const int lane = threadIdx.x & 63;
    float v0 = 0.f, v1 = 0.f, v2 = 0.f;
    if (valid) {
        v0 = xrow[lane];
        v1 = xrow[lane + 64];
        if (lane < 32) v2 = xrow[lane + 128];
    }
    float s  = v0 + v1 + v2;
    float sq = v0 * v0 + v1 * v1 + v2 * v2;
#pragma unroll
    for (int off = 32; off; off >>= 1) { s += __shfl_xor(s, off); sq += __shfl_xor(sq, off); }
    const float mean = s * (1.0f / DIM);
    const float var  = sq * (1.0f / DIM) - mean * mean;
    const float rs   = rsqrtf(var + EPS);
    ushort* orow = xn + (size_t)row * DIM;
    orow[lane]      = f2bfbits((v0 - mean) * rs * g[lane]      + b[lane]);
    orow[lane + 64] = f2bfbits((v1 - mean) * rs * g[lane + 64] + b[lane + 64]);
    if (lane < 32) orow[lane + 128] = f2bfbits((v2 - mean) * rs * g[lane + 128] + b[lane + 128]);
}

// ---------------------------------------------------------------- MFMA GEMM
// C[m,n] = sum_k A[m,k] * Wb[n,k] + bias[n].  K == 160, A bf16.
// 512 threads = 8 waves: 4 m-strips x 2 n-halves; swapped operands so
// lane holds 4 consecutive n for one token -> vector epilogue. Each block
// loops GSTRIPS m-strips with its weight panel resident.
template <int EPI>
__global__ __launch_bounds__(512) void gemm_mfma(
    const ushort* __restrict__ A, const ushort* __restrict__ Wb,
    const float* __restrict__ bias, void* __restrict__ Cv,
    const float* __restrict__ extra, int M, int N)
{
    __shared__ ushort Bs[160][164];
    const int tid = threadIdx.x;
    const int wv = tid >> 6, ln = tid & 63;
    const int g = ln >> 4, l15 = ln & 15;
    const int wvm = wv & 3, wvn = wv >> 2;
    const int n0 = blockIdx.y * 160;
    const int strip0 = blockIdx.x * GSTRIPS;

    for (int e = tid; e < 160 * 20; e += 512) {
        const int row = e / 20, part = e % 20;
        *(int4*)&Bs[row][part * 8] =
            *(const int4*)(Wb + (size_t)(n0 + row) * 160 + part * 8);
    }

    s16x8 a[2][5];
    {   // strip 0 A-frags
        const int m0 = strip0 * 128;
#pragma unroll
        for (int mt = 0; mt < 2; ++mt) {
            int am = m0 + wvm * 32 + mt * 16 + l15; if (am >= M) am = M - 1;
            const ushort* ap = A + (size_t)am * 160 + g * 8;
#pragma unroll
            for (int s = 0; s < 5; ++s) a[mt][s] = *(const s16x8*)(ap + s * 32);
        }
    }
    __syncthreads();

    for (int s = 0; s < GSTRIPS; ++s) {
        const int m0 = (strip0 + s) * 128;
        if (m0 >= M) break;

        f32x4 acc[2][5] = {};
#pragma unroll
        for (int j = 0; j < 5; ++j) {
#pragma unroll
            for (int nt = 0; nt < 5; ++nt) {
                const s16x8 bf = *(const s16x8*)&Bs[wvn * 80 + nt * 16 + l15][j * 32 + g * 8];
                acc[0][nt] = __builtin_amdgcn_mfma_f32_16x16x32_bf16(bf, a[0][j], acc[0][nt], 0, 0, 0);
                acc[1][nt] = __builtin_amdgcn_mfma_f32_16x16x32_bf16(bf, a[1][j], acc[1][nt], 0, 0, 0);
            }
        }

        if (s + 1 < GSTRIPS) {
            const int mn = (strip0 + s + 1) * 128;
#pragma unroll
            for (int mt = 0; mt < 2; ++mt) {
                int am = mn + wvm * 32 + mt * 16 + l15; if (am >= M) am = M - 1;
                const ushort* ap = A + (size_t)am * 160 + g * 8;
#pragma unroll
                for (int jj = 0; jj < 5; ++jj) a[mt][jj] = *(const s16x8*)(ap + jj * 32);
            }
        }

#pragma unroll
        for (int mt = 0; mt < 2; ++mt) {
            const int m = m0 + wvm * 32 + mt * 16 + l15;
            if (m >= M) continue;
            if (EPI == 0) {
                ushort* orow = (ushort*)Cv + (size_t)m * N;
#pragma unroll
                for (int nt = 0; nt < 5; ++nt) {
                    const int n = n0 + wvn * 80 + nt * 16 + g * 4;
                    const float4 bn = *(const float4*)&bias[n];
                    const float sc = ((n % 96) < 32) ? CS : 1.0f;
                    u16x4 o = { f2bfbits((acc[mt][nt][0] + bn.x) * sc),
                                f2bfbits((acc[mt][nt][1] + bn.y) * sc),
                                f2bfbits((acc[mt][nt][2] + bn.z) * sc),
                                f2bfbits((acc[mt][nt][3] + bn.w) * sc) };
                    *(u16x4*)(orow + n) = o;
                }
            } else {
                const int win = m / NTOK, tok = m % NTOK;
                const int bb = win / 25, wr = (win % 25) / 5, wc = win % 5;
                const int gh = wr * WS + tok / WS, gw = wc * WS + tok % WS;
                if (gh < H_ && gw < W_) {
                    const size_t rowoff = ((size_t)bb * L_ + (size_t)gh * W_ + gw) * DIM;
                    float* orow = (float*)Cv + rowoff;
                    const float* erow = extra + rowoff;
#pragma unroll
                    for (int nt = 0; nt < 5; ++nt) {
                        const int n = n0 + wvn * 80 + nt * 16 + g * 4;
                        const float4 bn = *(const float4*)&bias[n];
                        const float4 res = *(const float4*)&erow[n];
                        float4 o4 = { res.x + acc[mt][nt][0] + bn.x,
                                      res.y + acc[mt][nt][1] + bn.y,
                                      res.z + acc[mt][nt][2] + bn.z,
                                      res.w + acc[mt][nt][3] + bn.w };
                        *(float4*)&orow[n] = o4;
                    }
                }
            }
        }
    }
}

// ---------------------------------------------------------------- fused MLP
// 512 threads = 8 waves x 16 tokens = 128 tokens/block: one panel staging
// serves 2x the tokens of the previous version (half traffic, half barriers).
__global__ __launch_bounds__(512, 4) void mlp_fused(
    float* xo, const ushort* __restrict__ w1p, const ushort* __restrict__ w2p,
    const float* __restrict__ fc1_b, const float* __restrict__ fc2_b,
    const float* __restrict__ lng, const float* __restrict__ lnb)
{
    __shared__ ushort W1s[10240];
    __shared__ ushort W2s[10240];
    const int tid = threadIdx.x;
    const int wv = tid >> 6, ln = tid & 63;
    const int g = ln >> 4, l15 = ln & 15;
    const int row0 = blockIdx.x * 128 + wv * 16;

    // ---- LN2 in registers (1 m-tile per wave)
    const float* xp = xo + (size_t)(row0 + l15) * DIM + g * 8;
    float4 va[10];
    float vsum = 0.f, vsq = 0.f;
#pragma unroll
    for (int s = 0; s < 5; ++s) {
        const float4 p0 = *(const float4*)(xp + s * 32);
        const float4 p1 = *(const float4*)(xp + s * 32 + 4);
        va[s * 2] = p0; va[s * 2 + 1] = p1;
        vsum += (p0.x + p0.y) + (p0.z + p0.w) + (p1.x + p1.y) + (p1.z + p1.w);
        vsq  += (p0.x*p0.x + p0.y*p0.y) + (p0.z*p0.z + p0.w*p0.w)
              + (p1.x*p1.x + p1.y*p1.y) + (p1.z*p1.z + p1.w*p1.w);
    }
    vsum += __shfl_xor(vsum, 16); vsum += __shfl_xor(vsum, 32);
    vsq  += __shfl_xor(vsq, 16);  vsq  += __shfl_xor(vsq, 32);
    const float mean = vsum * (1.0f / DIM);
    const float rs = rsqrtf(vsq * (1.0f / DIM) - mean * mean + EPS);
    s16x8 a1[5];
#pragma unroll
    for (int s = 0; s < 5; ++s) {
        const float4 g0 = *(const float4*)(lng + s * 32 + g * 8);
        const float4 g1 = *(const float4*)(lng + s * 32 + g * 8 + 4);
        const float4 bb0 = *(const float4*)(lnb + s * 32 + g * 8);
        const float4 bb1 = *(const float4*)(lnb + s * 32 + g * 8 + 4);
        const float4 p0 = va[s * 2], p1 = va[s * 2 + 1];
        ushort o[8];
        o[0] = f2bfbits((p0.x - mean) * rs * g0.x + bb0.x);
        o[1] = f2bfbits((p0.y - mean) * rs * g0.y + bb0.y);
        o[2] = f2bfbits((p0.z - mean) * rs * g0.z + bb0.z);
        o[3] = f2bfbits((p0.w - mean) * rs * g0.w + bb0.w);
        o[4] = f2bfbits((p1.x - mean) * rs * g1.x + bb1.x);
        o[5] = f2bfbits((p1.y - mean) * rs * g1.y + bb1.y);
        o[6] = f2bfbits((p1.z - mean) * rs * g1.z + bb1.z);
        o[7] = f2bfbits((p1.w - mean) * rs * g1.w + bb1.w);
        a1[s] = *(const s16x8*)o;
    }

    f32x4 oacc[10] = {};
    for (int c = 0; c < 10; ++c) {       // 64 hiddens per chunk
        if (c) __syncthreads();
        const ushort* s1 = w1p + c * 10240;
        const ushort* s2 = w2p + c * 10240;
        for (int e = tid; e < 1280; e += 512) {
            *(int4*)&W1s[e * 8] = *(const int4*)(s1 + e * 8);
            *(int4*)&W2s[e * 8] = *(const int4*)(s2 + e * 8);
        }
        __syncthreads();

#pragma unroll
        for (int p = 0; p < 2; ++p) {    // pair of fc1 tiles (32 hiddens)
            f32x4 h0 = {0.f,0.f,0.f,0.f}, h1 = {0.f,0.f,0.f,0.f};
#pragma unroll
            for (int jj = 0; jj < 5; ++jj) {
                const s16x8 wfe = *(const s16x8*)&W1s[(((p * 2) * 5 + jj) * 64 + ln) * 8];
                const s16x8 wfo = *(const s16x8*)&W1s[(((p * 2 + 1) * 5 + jj) * 64 + ln) * 8];
                h0 = __builtin_amdgcn_mfma_f32_16x16x32_bf16(wfe, a1[jj], h0, 0, 0, 0);
                h1 = __builtin_amdgcn_mfma_f32_16x16x32_bf16(wfo, a1[jj], h1, 0, 0, 0);
            }
            const int hb0 = c * 64 + p * 32 + g * 4;
            const float4 hbe = *(const float4*)(fc1_b + hb0);
            const float4 hbo = *(const float4*)(fc1_b + hb0 + 16);
            const float hbev[4] = { hbe.x, hbe.y, hbe.z, hbe.w };
            const float hbov[4] = { hbo.x, hbo.y, hbo.z, hbo.w };
            ushort pk[8];
#pragma unroll
            for (int r = 0; r < 4; ++r) {
                float v = h0[r] + hbev[r];
                float t = EXP2(-2.302259756f * fmaf(0.044715f * v * v, v, v));
                pk[r] = f2bfbits(v * __builtin_amdgcn_rcpf(1.0f + t));
                v = h1[r] + hbov[r];
                t = EXP2(-2.302259756f * fmaf(0.044715f * v * v, v, v));
                pk[4 + r] = f2bfbits(v * __builtin_amdgcn_rcpf(1.0f + t));
            }
            const s16x8 P = *(const s16x8*)pk;
#pragma unroll
            for (int dt = 0; dt < 10; ++dt) {
                const s16x8 w2f = *(const s16x8*)&W2s[((p * 10 + dt) * 64 + ln) * 8];
                oacc[dt] = __builtin_amdgcn_mfma_f32_16x16x32_bf16(P, w2f, oacc[dt], 0, 0, 0);
            }
        }
    }

    // ---- epilogue: residual RMW; C-layout col=dim(l15), row=token(g*4+r)
#pragma unroll
    for (int dt = 0; dt < 10; ++dt) {
        const float bn = fc2_b[dt * 16 + l15];
#pragma unroll
        for (int r = 0; r < 4; ++r) {
            const size_t off = (size_t)(row0 + g * 4 + r) * DIM + dt * 16 + l15;
            xo[off] += oacc[dt][r] + bn;
        }
    }
}

// ---------------------------------------------------------------- attention
// Bias tiles bf16 (pre-scaled by log2e), shift-converted into the MFMA C
// operand: halves the dominant L2 stream. Q pre-scaled in qkv epilogue.
__global__ __launch_bounds__(256) void attn_mfma_kernel(
    const ushort* __restrict__ qkv, const ushort* __restrict__ biasPb,
    ushort* __restrict__ out)
{
    __shared__ ushort Ks[208][40];
    __shared__ ushort VT[32][212];
    const int win = blockIdx.x / HEADS;
    const int h   = blockIdx.x % HEADS;
    const int tid = threadIdx.x;
    const size_t base = (size_t)win * NTOK;
    const ushort* qbase = qkv + base * 480 + h * 96;

    for (int e = tid; e < 208 * 4; e += 256) {
        const int row = e >> 2, part = e & 3;
        const int gr = row < NTOK ? row : NTOK - 1;
        *(int4*)&Ks[row][part * 8] = *(const int4*)(qbase + (size_t)gr * 480 + 32 + part * 8);
    }
    for (int e = tid; e < NTOK * 4; e += 256) {
        const int key = e >> 2, part = e & 3;
        int4 p = *(const int4*)(qbase + (size_t)key * 480 + 64 + part * 8);
        const ushort* u = (const ushort*)&p;
#pragma unroll
        for (int j = 0; j < 8; ++j) VT[part * 8 + j][key] = u[j];
    }
    for (int e = tid; e < 12 * 32; e += 256) VT[e & 31][NTOK + (e >> 5)] = 0;
    __syncthreads();

    const int wv = tid >> 6, ln = tid & 63, g = ln >> 4, l15 = ln & 15;

    for (int qt = wv; qt < 13; qt += 4) {
        const int qr = qt * 16 + l15;
        const int qc = qr < NTOK ? qr : NTOK - 1;
        const s16x8 qf = *(const s16x8*)(qbase + (size_t)qc * 480 + g * 8);
        const ushort* bq = biasPb + ((size_t)(h * 13 + qt) * 13) * 1024;

        f32x4 S[13];
#pragma unroll
        for (int kt = 0; kt < 13; ++kt) {
            const u16x4 bv = *(const u16x4*)(bq + kt * 1024 + ln * 4);
            S[kt] = (f32x4){ bf2f(bv[0]), bf2f(bv[1]), bf2f(bv[2]), bf2f(bv[3]) };
        }
#pragma unroll
        for (int kt = 0; kt < 13; ++kt) {
            const s16x8 kf = *(const s16x8*)&Ks[kt * 16 + l15][g * 8];
            S[kt] = __builtin_amdgcn_mfma_f32_16x16x32_bf16(kf, qf, S[kt], 0, 0, 0);
        }
        float mx = -1e30f;
#pragma unroll
        for (int kt = 0; kt < 13; ++kt) {
#pragma unroll
            for (int r = 0; r < 4; ++r) {
                if (kt == 12) {
                    const int key = 192 + g * 4 + r;
                    if (key >= NTOK) S[kt][r] = -1e30f;
                }
                mx = fmaxf(mx, S[kt][r]);
            }
        }
        mx = fmaxf(mx, __shfl_xor(mx, 16));
        mx = fmaxf(mx, __shfl_xor(mx, 32));

        float sum = 0.f;
        s16x4 P[13];
#pragma unroll
        for (int kt = 0; kt < 13; ++kt) {
            const float p0 = EXP2(S[kt][0] - mx);
            const float p1 = EXP2(S[kt][1] - mx);
            const float p2 = EXP2(S[kt][2] - mx);
            const float p3 = EXP2(S[kt][3] - mx);
            sum += (p0 + p1) + (p2 + p3);
            P[kt] = (s16x4){ (short)f2bfbits(p0), (short)f2bfbits(p1),
                             (short)f2bfbits(p2), (short)f2bfbits(p3) };
        }
        sum += __shfl_xor(sum, 16);
        sum += __shfl_xor(sum, 32);

        f32x4 o0 = {0.f,0.f,0.f,0.f}, o1 = {0.f,0.f,0.f,0.f};
#pragma unroll
        for (int kt = 0; kt < 13; ++kt) {
            const s16x4 vf0 = *(const s16x4*)&VT[l15][kt * 16 + g * 4];
            const s16x4 vf1 = *(const s16x4*)&VT[16 + l15][kt * 16 + g * 4];
            o0 = __builtin_amdgcn_mfma_f32_16x16x16bf16_1k(vf0, P[kt], o0, 0, 0, 0);
            o1 = __builtin_amdgcn_mfma_f32_16x16x16bf16_1k(vf1, P[kt], o1, 0, 0, 0);
        }
        if (qr < NTOK) {
            const float inv = 1.0f / sum;
            ushort* op = out + (base + qr) * DIM + h * KD;
            u16x4 w0 = { f2bfbits(o0[0] * inv), f2bfbits(o0[1] * inv),
                         f2bfbits(o0[2] * inv), f2bfbits(o0[3] * inv) };
            u16x4 w1 = { f2bfbits(o1[0] * inv), f2bfbits(o1[1] * inv),
                         f2bfbits(o1[2] * inv), f2bfbits(o1[3] * inv) };
            *(u16x4*)(op + g * 4)      = w0;
            *(u16x4*)(op + 16 + g * 4) = w1;
        }
    }
}

// ---------------------------------------------------------------- dw conv + BN
__global__ __launch_bounds__(256) void dwconv_bn_kernel(
    const float* __restrict__ xin, const float* __restrict__ cwT,
    const float* __restrict__ bnb, float* __restrict__ xout)
{
    const int gid = blockIdx.x * 256 + threadIdx.x;   // MROW*40
    const int pos = gid / 40, c4 = (gid % 40) * 4;
    const int bb = pos >> 12, hw = pos & 4095;
    const int hh = hw >> 6, ww = hw & 63;
    float4 acc = *(const float4*)&bnb[c4];
#pragma unroll
    for (int kh = -1; kh <= 1; ++kh) {
        const int ih = hh + kh;
        if (ih < 0 || ih >= H_) continue;
#pragma unroll
        for (int kw = -1; kw <= 1; ++kw) {
            const int iw = ww + kw;
            if (iw < 0 || iw >= W_) continue;
            const float4 xv = *(const float4*)&xin[((size_t)(bb << 12) + (ih << 6) + iw) * DIM + c4];
            const float4 wv = *(const float4*)&cwT[((kh + 1) * 3 + (kw + 1)) * DIM + c4];
            acc.x = fmaf(xv.x, wv.x, acc.x);
            acc.y = fmaf(xv.y, wv.y, acc.y);
            acc.z = fmaf(xv.z, wv.z, acc.z);
            acc.w = fmaf(xv.w, wv.w, acc.w);
        }
    }
    *(float4*)&xout[(size_t)pos * DIM + c4] = acc;
}

// ---------------------------------------------------------------- launch
extern "C" void kernel_launch(void* const* d_in, const int* in_sizes, int n_in,
                              void* d_out, int out_size, void* d_ws, size_t ws_size,
                              hipStream_t stream)
{
    const float* x      = (const float*)d_in[0];
    const float* ln1_g  = (const float*)d_in[1];
    const float* ln1_b  = (const float*)d_in[2];
    const float* qkv_w  = (const float*)d_in[3];
    const float* qkv_b  = (const float*)d_in[4];
    const float* proj_w = (const float*)d_in[5];
    const float* proj_b = (const float*)d_in[6];
    const float* abias  = (const float*)d_in[7];
    const float* conv_w = (const float*)d_in[8];
    const float* bn_g   = (const float*)d_in[9];
    const float* bn_b   = (const float*)d_in[10];
    const float* ln2_g  = (const float*)d_in[11];
    const float* ln2_b  = (const float*)d_in[12];
    const float* fc1_w  = (const float*)d_in[13];
    const float* fc1_b  = (const float*)d_in[14];
    const float* fc2_w  = (const float*)d_in[15];
    const float* fc2_b  = (const float*)d_in[16];
    const int*   bidx   = (const int*)d_in[17];
    const int    n_off  = in_sizes[7] / HEADS;

    char* ws = (char*)d_ws;
    // [0,          25,088,000)  xn  bf16 78400x160   (dead after qkv gemm)
    // [25,088,000, 100,352,000) qkv bf16 78400x480   (dead after attn)
    // [100,352,000,125,440,000) ao  bf16 78400x160   (dead after proj)
    // [125,440,000,127,170,560) biasPb bf16 5x13x13x256x4 (overlaps x1; attn
    //                            reads it before proj writes x1)
    // [125,440,000,167,383,040) x1  f32 65536x160    (dead after conv)
    // [167,383,040,167,997,440) wb  bf16 (qkv|proj|W1pack|W2pack)
    // [167,997,440,168,003,200) cwT f32 9x160 (BN-folded)
    ushort* xn     = (ushort*)(ws);
    ushort* qkv    = (ushort*)(ws + 25088000);
    ushort* ao     = (ushort*)(ws + 100352000);
    ushort* biasPb = (ushort*)(ws + 125440000);
    float*  x1     = (float*)(ws + 125440000);
    ushort* wb     = (ushort*)(ws + 167383040);
    float*  cwT    = (float*)(ws + 167997440);
    float*  x2     = (float*)d_out;

    const int mblocks = (NROW + 128 * GSTRIPS - 1) / (128 * GSTRIPS);  // 154

    pre_kernel<<<dim3(1047), dim3(256), 0, stream>>>(
        qkv_w, proj_w, fc1_w, fc2_w, conv_w, bn_g, abias, bidx, wb, cwT, biasPb, n_off);

    ln1_win_kernel<<<dim3(NROW / 4), dim3(256), 0, stream>>>(x, ln1_g, ln1_b, xn);

    gemm_mfma<0><<<dim3(mblocks, 3), dim3(512), 0, stream>>>(
        xn, wb, qkv_b, (void*)qkv, nullptr, NROW, 480);

    attn_mfma_kernel<<<dim3(NWIN * HEADS), dim3(256), 0, stream>>>(qkv, biasPb, ao);

    gemm_mfma<1><<<dim3(mblocks, 1), dim3(512), 0, stream>>>(
        ao, wb + 76800, proj_b, (void*)x1, x, NROW, 160);

    dwconv_bn_kernel<<<dim3(MROW * 40 / 256), dim3(256), 0, stream>>>(
        x1, cwT, bn_b, x2);

    mlp_fused<<<dim3(MROW / 128), dim3(512), 0, stream>>>(
        x2, wb + 102400, wb + 204800, fc1_b, fc2_b, ln2_g, ln2_b);
}

// Round 14
// 232.630 us; speedup vs baseline: 1.0316x; 1.0316x over previous
//
#include <hip/hip_runtime.h>
#include <hip/hip_bf16.h>
#include <math.h>

typedef unsigned short ushort;
typedef __attribute__((ext_vector_type(4))) float f32x4;
typedef __attribute__((ext_vector_type(8))) short s16x8;
typedef __attribute__((ext_vector_type(4))) short s16x4;
typedef __attribute__((ext_vector_type(4))) ushort u16x4;

#define H_    64
#define W_    64
#define DIM   160
#define HEADS 5
#define KD    32
#define WS    14
#define NTOK  196
#define NWIN  400
#define HIDDEN 640
#define EPS   1e-5f
#define NROW  (NWIN*NTOK)    // 78400
#define BATCH 16
#define L_    (H_*W_)
#define MROW  (BATCH*L_)     // 65536
#define CS    0.25507875861f   // (1/sqrt(32)) * log2(e)
#define GSTRIPS 4

#if __has_builtin(__builtin_amdgcn_exp2f)
#define EXP2(x) __builtin_amdgcn_exp2f(x)
#else
#define EXP2(x) exp2f(x)
#endif

__device__ __forceinline__ ushort f2bfbits(float f) {
    unsigned u = __float_as_uint(f);
    unsigned r = (u + 0x7fffu + ((u >> 16) & 1u)) >> 16;
    return (ushort)r;
}
__device__ __forceinline__ float bf2f(ushort u) {
    return __uint_as_float(((unsigned)u) << 16);
}

// ---------------------------------------------------------------- pre kernel
// wb: [0,76800) qkv_w | [76800,102400) proj_w | [102400,204800) W1pack
// | [204800,307200) W2pack (all bf16).  biasPb: bf16 C-layout bias tiles,
// pre-scaled by log2e; padded keys get -1e30 (softmax-kill, no mask needed).
__global__ __launch_bounds__(256) void pre_kernel(
    const float* __restrict__ qkv_w, const float* __restrict__ proj_w,
    const float* __restrict__ fc1_w, const float* __restrict__ fc2_w,
    const float* __restrict__ conv_w, const float* __restrict__ bn_g,
    const float* __restrict__ abias, const int* __restrict__ bidx,
    ushort* __restrict__ wb, float* __restrict__ cwT,
    ushort* __restrict__ biasPb, int n_off)
{
    const int gid = blockIdx.x * 256 + threadIdx.x;
    if (gid < 19200) {
        float4 v = ((const float4*)qkv_w)[gid];
        u16x4 o = { f2bfbits(v.x), f2bfbits(v.y), f2bfbits(v.z), f2bfbits(v.w) };
        *(u16x4*)(wb + gid * 4) = o;
    } else if (gid < 25600) {
        const int i = gid - 19200;
        float4 v = ((const float4*)proj_w)[i];
        u16x4 o = { f2bfbits(v.x), f2bfbits(v.y), f2bfbits(v.z), f2bfbits(v.w) };
        *(u16x4*)(wb + 76800 + i * 4) = o;
    } else if (gid < 38400) {
        const int idx = gid - 25600;          // [0,12800)
        const int l = idx & 63, rest = idx >> 6;
        const int jj = rest % 5, ht = rest / 5;
        const float* src = fc1_w + (size_t)(ht * 16 + (l & 15)) * 160
                         + jj * 32 + (l >> 4) * 8;
        const float4 v0 = *(const float4*)src;
        const float4 v1 = *(const float4*)(src + 4);
        u16x4 o0 = { f2bfbits(v0.x), f2bfbits(v0.y), f2bfbits(v0.z), f2bfbits(v0.w) };
        u16x4 o1 = { f2bfbits(v1.x), f2bfbits(v1.y), f2bfbits(v1.z), f2bfbits(v1.w) };
        *(u16x4*)(wb + 102400 + idx * 8)     = o0;
        *(u16x4*)(wb + 102400 + idx * 8 + 4) = o1;
    } else if (gid < 51200) {
        const int idx = gid - 38400;          // [0,12800)
        const int l = idx & 63, f = idx >> 6; // f in [0,200)
        const int dt = f % 10, u = f / 10;
        const float* base = fc2_w + (size_t)(dt * 16 + (l & 15)) * HIDDEN
                          + u * 32 + 4 * (l >> 4);
        const float4 v0 = *(const float4*)base;          // i=0..3 (even tile)
        const float4 v1 = *(const float4*)(base + 16);   // i=4..7 (odd tile)
        u16x4 o0 = { f2bfbits(v0.x), f2bfbits(v0.y), f2bfbits(v0.z), f2bfbits(v0.w) };
        u16x4 o1 = { f2bfbits(v1.x), f2bfbits(v1.y), f2bfbits(v1.z), f2bfbits(v1.w) };
        *(u16x4*)(wb + 204800 + idx * 8)     = o0;
        *(u16x4*)(wb + 204800 + idx * 8 + 4) = o1;
    } else if (gid < 51560) {
        const int i = gid - 51200;
        const int t = i / 40, c4 = (i % 40) * 4;
#pragma unroll
        for (int j = 0; j < 4; ++j) {
            const int c = c4 + j;
            cwT[t * DIM + c] = conv_w[c * 9 + t] * bn_g[c] * rsqrtf(1.0f + EPS);
        }
    } else if (gid < 267880) {
        const int idx = gid - 51560;          // [0,216320)
        const int ln = idx & 255, f = idx >> 8;  // f in [0,845)
        const int h = f / 169, rem = f % 169;
        const int qt = rem / 13, kt = rem % 13;
        int q = qt * 16 + (ln & 15); if (q > NTOK - 1) q = NTOK - 1;
        const int k0 = kt * 16 + (ln >> 4) * 4;
        ushort o[4];
#pragma unroll
        for (int r = 0; r < 4; ++r) {
            const int k = k0 + r;
            o[r] = (k < NTOK)
                ? f2bfbits(abias[h * n_off + bidx[q * NTOK + k]] * 1.4426950408889634f)
                : f2bfbits(-1e30f);
        }
        *(u16x4*)(biasPb + (size_t)idx * 4) = *(const u16x4*)o;
    }
}

// ---------------------------------------------------------------- LN1
__global__ __launch_bounds__(256) void ln1_win_kernel(
    const float* __restrict__ x, const float* __restrict__ g,
    const float* __restrict__ b, ushort* __restrict__ xn)
{
    const int row = blockIdx.x * 4 + (threadIdx.x >> 6);
    const int win = row / NTOK, tok = row % NTOK;
    const int bb = win / 25, wr = (win % 25) / 5, wc = win % 5;
    const int gh = wr * WS + tok / WS, gw = wc * WS + tok % WS;
    const bool valid = (gh < H_) && (gw < W_);
    const float* xrow = x + ((size_t)bb * L_ + (size_t)gh * W_ + gw) * DIM;
    const int lane = threadIdx.x & 63;
    float v0 = 0.f, v1 = 0.f, v2 = 0.f;
    if (valid) {
        v0 = xrow[lane];
        v1 = xrow[lane + 64];
        if (lane < 32) v2 = xrow[lane + 128];
    }
    float s  = v0 + v1 + v2;
    float sq = v0 * v0 + v1 * v1 + v2 * v2;
#pragma unroll
    for (int off = 32; off; off >>= 1) { s += __shfl_xor(s, off); sq += __shfl_xor(sq, off); }
    const float mean = s * (1.0f / DIM);
    const float var  = sq * (1.0f / DIM) - mean * mean;
    const float rs   = rsqrtf(var + EPS);
    ushort* orow = xn + (size_t)row * DIM;
    orow[lane]      = f2bfbits((v0 - mean) * rs * g[lane]      + b[lane]);
    orow[lane + 64] = f2bfbits((v1 - mean) * rs * g[lane + 64] + b[lane + 64]);
    if (lane < 32) orow[lane + 128] = f2bfbits((v2 - mean) * rs * g[lane + 128] + b[lane + 128]);
}

// ---------------------------------------------------------------- MFMA GEMM
template <int EPI>
__global__ __launch_bounds__(512) void gemm_mfma(
    const ushort* __restrict__ A, const ushort* __restrict__ Wb,
    const float* __restrict__ bias, void* __restrict__ Cv,
    const float* __restrict__ extra, int M, int N)
{
    __shared__ ushort Bs[160][164];
    const int tid = threadIdx.x;
    const int wv = tid >> 6, ln = tid & 63;
    const int g = ln >> 4, l15 = ln & 15;
    const int wvm = wv & 3, wvn = wv >> 2;
    const int n0 = blockIdx.y * 160;
    const int strip0 = blockIdx.x * GSTRIPS;

    for (int e = tid; e < 160 * 20; e += 512) {
        const int row = e / 20, part = e % 20;
        *(int4*)&Bs[row][part * 8] =
            *(const int4*)(Wb + (size_t)(n0 + row) * 160 + part * 8);
    }

    s16x8 a[2][5];
    {   // strip 0 A-frags
        const int m0 = strip0 * 128;
#pragma unroll
        for (int mt = 0; mt < 2; ++mt) {
            int am = m0 + wvm * 32 + mt * 16 + l15; if (am >= M) am = M - 1;
            const ushort* ap = A + (size_t)am * 160 + g * 8;
#pragma unroll
            for (int s = 0; s < 5; ++s) a[mt][s] = *(const s16x8*)(ap + s * 32);
        }
    }
    __syncthreads();

    for (int s = 0; s < GSTRIPS; ++s) {
        const int m0 = (strip0 + s) * 128;
        if (m0 >= M) break;

        f32x4 acc[2][5] = {};
#pragma unroll
        for (int j = 0; j < 5; ++j) {
#pragma unroll
            for (int nt = 0; nt < 5; ++nt) {
                const s16x8 bf = *(const s16x8*)&Bs[wvn * 80 + nt * 16 + l15][j * 32 + g * 8];
                acc[0][nt] = __builtin_amdgcn_mfma_f32_16x16x32_bf16(bf, a[0][j], acc[0][nt], 0, 0, 0);
                acc[1][nt] = __builtin_amdgcn_mfma_f32_16x16x32_bf16(bf, a[1][j], acc[1][nt], 0, 0, 0);
            }
        }

        if (s + 1 < GSTRIPS) {
            const int mn = (strip0 + s + 1) * 128;
#pragma unroll
            for (int mt = 0; mt < 2; ++mt) {
                int am = mn + wvm * 32 + mt * 16 + l15; if (am >= M) am = M - 1;
                const ushort* ap = A + (size_t)am * 160 + g * 8;
#pragma unroll
                for (int jj = 0; jj < 5; ++jj) a[mt][jj] = *(const s16x8*)(ap + jj * 32);
            }
        }

#pragma unroll
        for (int mt = 0; mt < 2; ++mt) {
            const int m = m0 + wvm * 32 + mt * 16 + l15;
            if (m >= M) continue;
            if (EPI == 0) {
                ushort* orow = (ushort*)Cv + (size_t)m * N;
#pragma unroll
                for (int nt = 0; nt < 5; ++nt) {
                    const int n = n0 + wvn * 80 + nt * 16 + g * 4;
                    const float4 bn = *(const float4*)&bias[n];
                    const float sc = ((n % 96) < 32) ? CS : 1.0f;
                    u16x4 o = { f2bfbits((acc[mt][nt][0] + bn.x) * sc),
                                f2bfbits((acc[mt][nt][1] + bn.y) * sc),
                                f2bfbits((acc[mt][nt][2] + bn.z) * sc),
                                f2bfbits((acc[mt][nt][3] + bn.w) * sc) };
                    *(u16x4*)(orow + n) = o;
                }
            } else {
                const int win = m / NTOK, tok = m % NTOK;
                const int bb = win / 25, wr = (win % 25) / 5, wc = win % 5;
                const int gh = wr * WS + tok / WS, gw = wc * WS + tok % WS;
                if (gh < H_ && gw < W_) {
                    const size_t rowoff = ((size_t)bb * L_ + (size_t)gh * W_ + gw) * DIM;
                    float* orow = (float*)Cv + rowoff;
                    const float* erow = extra + rowoff;
#pragma unroll
                    for (int nt = 0; nt < 5; ++nt) {
                        const int n = n0 + wvn * 80 + nt * 16 + g * 4;
                        const float4 bn = *(const float4*)&bias[n];
                        const float4 res = *(const float4*)&erow[n];
                        float4 o4 = { res.x + acc[mt][nt][0] + bn.x,
                                      res.y + acc[mt][nt][1] + bn.y,
                                      res.z + acc[mt][nt][2] + bn.z,
                                      res.w + acc[mt][nt][3] + bn.w };
                        *(float4*)&orow[n] = o4;
                    }
                }
            }
        }
    }
}

// ---------------------------------------------------------------- fused MLP
// (r12 256-thread config — best measured)
__global__ __launch_bounds__(256, 3) void mlp_fused(
    float* xo, const ushort* __restrict__ w1p, const ushort* __restrict__ w2p,
    const float* __restrict__ fc1_b, const float* __restrict__ fc2_b,
    const float* __restrict__ lng, const float* __restrict__ lnb)
{
    __shared__ ushort W1s[10240];
    __shared__ ushort W2s[10240];
    const int tid = threadIdx.x;
    const int wv = tid >> 6, ln = tid & 63;
    const int g = ln >> 4, l15 = ln & 15;
    const int row0 = blockIdx.x * 64 + wv * 16;

    const float* xp = xo + (size_t)(row0 + l15) * DIM + g * 8;
    float4 va[10];
    float vsum = 0.f, vsq = 0.f;
#pragma unroll
    for (int s = 0; s < 5; ++s) {
        const float4 p0 = *(const float4*)(xp + s * 32);
        const float4 p1 = *(const float4*)(xp + s * 32 + 4);
        va[s * 2] = p0; va[s * 2 + 1] = p1;
        vsum += (p0.x + p0.y) + (p0.z + p0.w) + (p1.x + p1.y) + (p1.z + p1.w);
        vsq  += (p0.x*p0.x + p0.y*p0.y) + (p0.z*p0.z + p0.w*p0.w)
              + (p1.x*p1.x + p1.y*p1.y) + (p1.z*p1.z + p1.w*p1.w);
    }
    vsum += __shfl_xor(vsum, 16); vsum += __shfl_xor(vsum, 32);
    vsq  += __shfl_xor(vsq, 16);  vsq  += __shfl_xor(vsq, 32);
    const float mean = vsum * (1.0f / DIM);
    const float rs = rsqrtf(vsq * (1.0f / DIM) - mean * mean + EPS);
    s16x8 a1[5];
#pragma unroll
    for (int s = 0; s < 5; ++s) {
        const float4 g0 = *(const float4*)(lng + s * 32 + g * 8);
        const float4 g1 = *(const float4*)(lng + s * 32 + g * 8 + 4);
        const float4 bb0 = *(const float4*)(lnb + s * 32 + g * 8);
        const float4 bb1 = *(const float4*)(lnb + s * 32 + g * 8 + 4);
        const float4 p0 = va[s * 2], p1 = va[s * 2 + 1];
        ushort o[8];
        o[0] = f2bfbits((p0.x - mean) * rs * g0.x + bb0.x);
        o[1] = f2bfbits((p0.y - mean) * rs * g0.y + bb0.y);
        o[2] = f2bfbits((p0.z - mean) * rs * g0.z + bb0.z);
        o[3] = f2bfbits((p0.w - mean) * rs * g0.w + bb0.w);
        o[4] = f2bfbits((p1.x - mean) * rs * g1.x + bb1.x);
        o[5] = f2bfbits((p1.y - mean) * rs * g1.y + bb1.y);
        o[6] = f2bfbits((p1.z - mean) * rs * g1.z + bb1.z);
        o[7] = f2bfbits((p1.w - mean) * rs * g1.w + bb1.w);
        a1[s] = *(const s16x8*)o;
    }

    f32x4 oacc[10] = {};
    for (int c = 0; c < 10; ++c) {
        if (c) __syncthreads();
        const ushort* s1 = w1p + c * 10240;
        const ushort* s2 = w2p + c * 10240;
        for (int e = tid; e < 1280; e += 256) {
            *(int4*)&W1s[e * 8] = *(const int4*)(s1 + e * 8);
            *(int4*)&W2s[e * 8] = *(const int4*)(s2 + e * 8);
        }
        __syncthreads();

#pragma unroll
        for (int p = 0; p < 2; ++p) {
            f32x4 h0 = {0.f,0.f,0.f,0.f}, h1 = {0.f,0.f,0.f,0.f};
#pragma unroll
            for (int jj = 0; jj < 5; ++jj) {
                const s16x8 wfe = *(const s16x8*)&W1s[(((p * 2) * 5 + jj) * 64 + ln) * 8];
                const s16x8 wfo = *(const s16x8*)&W1s[(((p * 2 + 1) * 5 + jj) * 64 + ln) * 8];
                h0 = __builtin_amdgcn_mfma_f32_16x16x32_bf16(wfe, a1[jj], h0, 0, 0, 0);
                h1 = __builtin_amdgcn_mfma_f32_16x16x32_bf16(wfo, a1[jj], h1, 0, 0, 0);
            }
            const int hb0 = c * 64 + p * 32 + g * 4;
            const float4 hbe = *(const float4*)(fc1_b + hb0);
            const float4 hbo = *(const float4*)(fc1_b + hb0 + 16);
            const float hbev[4] = { hbe.x, hbe.y, hbe.z, hbe.w };
            const float hbov[4] = { hbo.x, hbo.y, hbo.z, hbo.w };
            ushort pk[8];
#pragma unroll
            for (int r = 0; r < 4; ++r) {
                float v = h0[r] + hbev[r];
                float t = EXP2(-2.302259756f * fmaf(0.044715f * v * v, v, v));
                pk[r] = f2bfbits(v * __builtin_amdgcn_rcpf(1.0f + t));
                v = h1[r] + hbov[r];
                t = EXP2(-2.302259756f * fmaf(0.044715f * v * v, v, v));
                pk[4 + r] = f2bfbits(v * __builtin_amdgcn_rcpf(1.0f + t));
            }
            const s16x8 P = *(const s16x8*)pk;
#pragma unroll
            for (int dt = 0; dt < 10; ++dt) {
                const s16x8 w2f = *(const s16x8*)&W2s[((p * 10 + dt) * 64 + ln) * 8];
                oacc[dt] = __builtin_amdgcn_mfma_f32_16x16x32_bf16(P, w2f, oacc[dt], 0, 0, 0);
            }
        }
    }

#pragma unroll
    for (int dt = 0; dt < 10; ++dt) {
        const float bn = fc2_b[dt * 16 + l15];
#pragma unroll
        for (int r = 0; r < 4; ++r) {
            const size_t off = (size_t)(row0 + g * 4 + r) * DIM + dt * 16 + l15;
            xo[off] += oacc[dt][r] + bn;
        }
    }
}

// ---------------------------------------------------------------- attention
// No max-subtraction (scores provably tiny; padded keys killed via -1e30
// bias). PV paired into full-rate 16x16x32 via the sigma-permutation:
// A = concat{VT[d][32u+4g..], VT[d][32u+16+4g..]}, B = concat{P[2u],P[2u+1]}.
__global__ __launch_bounds__(256) void attn_mfma_kernel(
    const ushort* __restrict__ qkv, const ushort* __restrict__ biasPb,
    ushort* __restrict__ out)
{
    __shared__ ushort Ks[208][40];
    __shared__ ushort VT[32][228];
    const int win = blockIdx.x / HEADS;
    const int h   = blockIdx.x % HEADS;
    const int tid = threadIdx.x;
    const size_t base = (size_t)win * NTOK;
    const ushort* qbase = qkv + base * 480 + h * 96;

    for (int e = tid; e < 208 * 4; e += 256) {
        const int row = e >> 2, part = e & 3;
        const int gr = row < NTOK ? row : NTOK - 1;
        *(int4*)&Ks[row][part * 8] = *(const int4*)(qbase + (size_t)gr * 480 + 32 + part * 8);
    }
    for (int e = tid; e < NTOK * 4; e += 256) {
        const int key = e >> 2, part = e & 3;
        int4 p = *(const int4*)(qbase + (size_t)key * 480 + 64 + part * 8);
        const ushort* u = (const ushort*)&p;
#pragma unroll
        for (int j = 0; j < 8; ++j) VT[part * 8 + j][key] = u[j];
    }
    for (int e = tid; e < 28 * 32; e += 256) VT[e & 31][NTOK + (e >> 5)] = 0;
    __syncthreads();

    const int wv = tid >> 6, ln = tid & 63, g = ln >> 4, l15 = ln & 15;

    for (int qt = wv; qt < 13; qt += 4) {
        const int qr = qt * 16 + l15;
        const int qc = qr < NTOK ? qr : NTOK - 1;
        const s16x8 qf = *(const s16x8*)(qbase + (size_t)qc * 480 + g * 8);
        const ushort* bq = biasPb + ((size_t)(h * 13 + qt) * 13) * 1024;

        f32x4 S[13];
#pragma unroll
        for (int kt = 0; kt < 13; ++kt) {
            const u16x4 bv = *(const u16x4*)(bq + kt * 1024 + ln * 4);
            S[kt] = (f32x4){ bf2f(bv[0]), bf2f(bv[1]), bf2f(bv[2]), bf2f(bv[3]) };
        }
#pragma unroll
        for (int kt = 0; kt < 13; ++kt) {
            const s16x8 kf = *(const s16x8*)&Ks[kt * 16 + l15][g * 8];
            S[kt] = __builtin_amdgcn_mfma_f32_16x16x32_bf16(kf, qf, S[kt], 0, 0, 0);
        }

        float sum = 0.f;
        s16x8 Pp[7];
#pragma unroll
        for (int kt = 0; kt < 13; ++kt) {
            const float p0 = EXP2(S[kt][0]);
            const float p1 = EXP2(S[kt][1]);
            const float p2 = EXP2(S[kt][2]);
            const float p3 = EXP2(S[kt][3]);
            sum += (p0 + p1) + (p2 + p3);
            const int u = kt >> 1, hi = (kt & 1) * 4;
            Pp[u][hi + 0] = (short)f2bfbits(p0);
            Pp[u][hi + 1] = (short)f2bfbits(p1);
            Pp[u][hi + 2] = (short)f2bfbits(p2);
            Pp[u][hi + 3] = (short)f2bfbits(p3);
        }
        Pp[6][4] = 0; Pp[6][5] = 0; Pp[6][6] = 0; Pp[6][7] = 0;
        sum += __shfl_xor(sum, 16);
        sum += __shfl_xor(sum, 32);

        f32x4 o0 = {0.f,0.f,0.f,0.f}, o1 = {0.f,0.f,0.f,0.f};
#pragma unroll
        for (int u = 0; u < 7; ++u) {
            const s16x4 a0lo = *(const s16x4*)&VT[l15][u * 32 + g * 4];
            const s16x4 a0hi = *(const s16x4*)&VT[l15][u * 32 + 16 + g * 4];
            const s16x4 a1lo = *(const s16x4*)&VT[16 + l15][u * 32 + g * 4];
            const s16x4 a1hi = *(const s16x4*)&VT[16 + l15][u * 32 + 16 + g * 4];
            const s16x8 A0 = { a0lo[0], a0lo[1], a0lo[2], a0lo[3],
                               a0hi[0], a0hi[1], a0hi[2], a0hi[3] };
            const s16x8 A1 = { a1lo[0], a1lo[1], a1lo[2], a1lo[3],
                               a1hi[0], a1hi[1], a1hi[2], a1hi[3] };
            o0 = __builtin_amdgcn_mfma_f32_16x16x32_bf16(A0, Pp[u], o0, 0, 0, 0);
            o1 = __builtin_amdgcn_mfma_f32_16x16x32_bf16(A1, Pp[u], o1, 0, 0, 0);
        }
        if (qr < NTOK) {
            const float inv = __builtin_amdgcn_rcpf(sum);
            ushort* op = out + (base + qr) * DIM + h * KD;
            u16x4 w0 = { f2bfbits(o0[0] * inv), f2bfbits(o0[1] * inv),
                         f2bfbits(o0[2] * inv), f2bfbits(o0[3] * inv) };
            u16x4 w1 = { f2bfbits(o1[0] * inv), f2bfbits(o1[1] * inv),
                         f2bfbits(o1[2] * inv), f2bfbits(o1[3] * inv) };
            *(u16x4*)(op + g * 4)      = w0;
            *(u16x4*)(op + 16 + g * 4) = w1;
        }
    }
}

// ---------------------------------------------------------------- dw conv + BN
__global__ __launch_bounds__(256) void dwconv_bn_kernel(
    const float* __restrict__ xin, const float* __restrict__ cwT,
    const float* __restrict__ bnb, float* __restrict__ xout)
{
    const int gid = blockIdx.x * 256 + threadIdx.x;   // MROW*40
    const int pos = gid / 40, c4 = (gid % 40) * 4;
    const int bb = pos >> 12, hw = pos & 4095;
    const int hh = hw >> 6, ww = hw & 63;
    float4 acc = *(const float4*)&bnb[c4];
#pragma unroll
    for (int kh = -1; kh <= 1; ++kh) {
        const int ih = hh + kh;
        if (ih < 0 || ih >= H_) continue;
#pragma unroll
        for (int kw = -1; kw <= 1; ++kw) {
            const int iw = ww + kw;
            if (iw < 0 || iw >= W_) continue;
            const float4 xv = *(const float4*)&xin[((size_t)(bb << 12) + (ih << 6) + iw) * DIM + c4];
            const float4 wv = *(const float4*)&cwT[((kh + 1) * 3 + (kw + 1)) * DIM + c4];
            acc.x = fmaf(xv.x, wv.x, acc.x);
            acc.y = fmaf(xv.y, wv.y, acc.y);
            acc.z = fmaf(xv.z, wv.z, acc.z);
            acc.w = fmaf(xv.w, wv.w, acc.w);
        }
    }
    *(float4*)&xout[(size_t)pos * DIM + c4] = acc;
}

// ---------------------------------------------------------------- launch
extern "C" void kernel_launch(void* const* d_in, const int* in_sizes, int n_in,
                              void* d_out, int out_size, void* d_ws, size_t ws_size,
                              hipStream_t stream)
{
    const float* x      = (const float*)d_in[0];
    const float* ln1_g  = (const float*)d_in[1];
    const float* ln1_b  = (const float*)d_in[2];
    const float* qkv_w  = (const float*)d_in[3];
    const float* qkv_b  = (const float*)d_in[4];
    const float* proj_w = (const float*)d_in[5];
    const float* proj_b = (const float*)d_in[6];
    const float* abias  = (const float*)d_in[7];
    const float* conv_w = (const float*)d_in[8];
    const float* bn_g   = (const float*)d_in[9];
    const float* bn_b   = (const float*)d_in[10];
    const float* ln2_g  = (const float*)d_in[11];
    const float* ln2_b  = (const float*)d_in[12];
    const float* fc1_w  = (const float*)d_in[13];
    const float* fc1_b  = (const float*)d_in[14];
    const float* fc2_w  = (const float*)d_in[15];
    const float* fc2_b  = (const float*)d_in[16];
    const int*   bidx   = (const int*)d_in[17];
    const int    n_off  = in_sizes[7] / HEADS;

    char* ws = (char*)d_ws;
    ushort* xn     = (ushort*)(ws);
    ushort* qkv    = (ushort*)(ws + 25088000);
    ushort* ao     = (ushort*)(ws + 100352000);
    ushort* biasPb = (ushort*)(ws + 125440000);
    float*  x1     = (float*)(ws + 125440000);
    ushort* wb     = (ushort*)(ws + 167383040);
    float*  cwT    = (float*)(ws + 167997440);
    float*  x2     = (float*)d_out;

    const int mblocks = (NROW + 128 * GSTRIPS - 1) / (128 * GSTRIPS);  // 154

    pre_kernel<<<dim3(1047), dim3(256), 0, stream>>>(
        qkv_w, proj_w, fc1_w, fc2_w, conv_w, bn_g, abias, bidx, wb, cwT, biasPb, n_off);

    ln1_win_kernel<<<dim3(NROW / 4), dim3(256), 0, stream>>>(x, ln1_g, ln1_b, xn);

    gemm_mfma<0><<<dim3(mblocks, 3), dim3(512), 0, stream>>>(
        xn, wb, qkv_b, (void*)qkv, nullptr, NROW, 480);

    attn_mfma_kernel<<<dim3(NWIN * HEADS), dim3(256), 0, stream>>>(qkv, biasPb, ao);

    gemm_mfma<1><<<dim3(mblocks, 1), dim3(512), 0, stream>>>(
        ao, wb + 76800, proj_b, (void*)x1, x, NROW, 160);

    dwconv_bn_kernel<<<dim3(MROW * 40 / 256), dim3(256), 0, stream>>>(
        x1, cwT, bn_b, x2);

    mlp_fused<<<dim3(MROW / 64), dim3(256), 0, stream>>>(
        x2, wb + 102400, wb + 204800, fc1_b, fc2_b, ln2_g, ln2_b);
}